// Round 3
// baseline (3406.375 us; speedup 1.0000x reference)
//
#include <hip/hip_runtime.h>
#include <math.h>

#define N_NODES 100000
#define N_EDGES 2500000
#define N_GRAPHS 512
#define IN_DIM 14
#define HID 32

// dst-buckets: bucket = dst >> 7 (128 nodes per bucket)
#define BSHIFT 7
#define BNODES 128
#define NBUCK 782            // ceil(100000 / 128)
#define BCAP 4096            // mean 3200, sigma ~57 -> 15.8 sigma slack
#define ACCP 33              // padded LDS leading dim (bank-conflict-free epilogue)

typedef unsigned int uint;
typedef unsigned short ushort;

__device__ inline float bfu2f(uint lo16) { return __uint_as_float(lo16 << 16); }
__device__ inline float bfhi2f(uint w) { return __uint_as_float(w & 0xffff0000u); }
__device__ inline ushort f2bf(float f) {
    uint u = __float_as_uint(f);
    return (ushort)((u + 0x7fffu + ((u >> 16) & 1u)) >> 16);  // RNE
}

// ============ bucket fill: one pass, 782 hot cursors ============
__global__ void bucket_fill(const int* __restrict__ src, const int* __restrict__ dst,
                            int* __restrict__ cursor, int* __restrict__ bucket) {
    int e = blockIdx.x * 256 + threadIdx.x;
    if (e >= N_EDGES) return;
    int d = dst[e];
    int b = d >> BSHIFT;
    int p = atomicAdd(&cursor[b], 1);
    if (p < BCAP) bucket[b * BCAP + p] = (src[e] << BSHIFT) | (d & (BNODES - 1));
}

// ============ layer-1 pre-GEMM: tmp(bf16) = x @ W_rel1 (14 -> 32) ============
__global__ void gemm14(const float* __restrict__ h, const float* __restrict__ W,
                       ushort* __restrict__ out) {
    __shared__ float sW[IN_DIM][HID];
    int t = threadIdx.x;
    for (int i = t; i < IN_DIM * HID; i += 256) sW[i / HID][i % HID] = W[i];
    __syncthreads();
    int idx = blockIdx.x * 256 + t;  // n*32 + o
    if (idx >= N_NODES * HID) return;
    int n = idx >> 5, o = idx & 31;
    const float* hr = h + (long)n * IN_DIM;
    float acc = 0.f;
#pragma unroll
    for (int k = 0; k < IN_DIM; ++k) acc += hr[k] * sW[k][o];
    out[idx] = f2bf(acc);
}

// ============ fused conv over one bucket ============
// 256 threads = 32 groups of 8 lanes; LDS f32 accumulator tile 128x32 (padded);
// epilogue: 2 threads per node, 16 outputs each.
template <bool MUL_REL, int K, bool ROOT_BF16>
__global__ void conv_bucket(const int* __restrict__ bucket, const int* __restrict__ cnt,
                            const ushort* __restrict__ featb,  // N x 32 bf16 gather table
                            const void* __restrict__ root_in,  // N x K (bf16 or f32)
                            const float* __restrict__ Wrel,    // 32x32 (if MUL_REL)
                            const float* __restrict__ bias,    // 32
                            const float* __restrict__ Wroot,   // K x 32
                            ushort* __restrict__ outb) {       // N x 32 bf16
    __shared__ float sacc[BNODES * ACCP];
    __shared__ float sWrel[HID * HID];
    __shared__ float sWroot[K * HID];
    __shared__ float sb[HID];
    int t = threadIdx.x;
    for (int i = t; i < BNODES * ACCP; i += 256) sacc[i] = 0.f;
    if (MUL_REL)
        for (int i = t; i < HID * HID; i += 256) sWrel[i] = Wrel[i];
    for (int i = t; i < K * HID; i += 256) sWroot[i] = Wroot[i];
    if (t < HID) sb[t] = bias[t];
    __syncthreads();

    int b = blockIdx.x;
    int base = b * BCAP;
    int nE = cnt[b]; if (nE > BCAP) nE = BCAP;
    int g = t >> 3, q = t & 7;

    for (int e = g; e < nE; e += 32) {
        int p = bucket[base + e];
        int sn = p >> BSHIFT;
        int ld = p & (BNODES - 1);
        const uint2 v = *(const uint2*)(featb + (size_t)sn * HID + q * 4);
        float f0 = bfu2f(v.x & 0xffffu), f1 = bfhi2f(v.x);
        float f2 = bfu2f(v.y & 0xffffu), f3 = bfhi2f(v.y);
        float* a = &sacc[ld * ACCP + q * 4];
        atomicAdd(a + 0, f0);
        atomicAdd(a + 1, f1);
        atomicAdd(a + 2, f2);
        atomicAdd(a + 3, f3);
    }
    __syncthreads();

    // epilogue
    int ln = t >> 1;
    int half = t & 1;
    int o0 = half * 16;
    int n = b * BNODES + ln;
    if (n >= N_NODES) return;

    float r[16];
#pragma unroll
    for (int o = 0; o < 16; ++o) r[o] = sb[o0 + o];

    if constexpr (MUL_REL) {
        for (int k = 0; k < HID; ++k) {
            float a = sacc[ln * ACCP + k];
            const float* w = &sWrel[k * HID + o0];
#pragma unroll
            for (int o = 0; o < 16; ++o) r[o] += a * w[o];
        }
    } else {
#pragma unroll
        for (int o = 0; o < 16; ++o) r[o] += sacc[ln * ACCP + o0 + o];
    }

    if constexpr (ROOT_BF16) {
        const uint4* hp = (const uint4*)((const ushort*)root_in + (size_t)n * HID);
        uint4 h0 = hp[0], h1 = hp[1], h2 = hp[2], h3 = hp[3];
        uint hw[16] = {h0.x, h0.y, h0.z, h0.w, h1.x, h1.y, h1.z, h1.w,
                       h2.x, h2.y, h2.z, h2.w, h3.x, h3.y, h3.z, h3.w};
#pragma unroll
        for (int m = 0; m < 16; ++m) {
            float e0 = bfu2f(hw[m] & 0xffffu);
            float e1 = bfhi2f(hw[m]);
            const float* w0 = &sWroot[(2 * m) * HID + o0];
            const float* w1 = &sWroot[(2 * m + 1) * HID + o0];
#pragma unroll
            for (int o = 0; o < 16; ++o) r[o] += e0 * w0[o] + e1 * w1[o];
        }
    } else {
        const float* hr = (const float*)root_in + (size_t)n * K;
        for (int k = 0; k < K; ++k) {
            float hv = hr[k];
            const float* w = &sWroot[k * HID + o0];
#pragma unroll
            for (int o = 0; o < 16; ++o) r[o] += hv * w[o];
        }
    }

    uint pw[8];
#pragma unroll
    for (int m = 0; m < 8; ++m) {
        ushort lo = f2bf(fmaxf(r[2 * m], 0.f));
        ushort hi = f2bf(fmaxf(r[2 * m + 1], 0.f));
        pw[m] = (uint)lo | ((uint)hi << 16);
    }
    uint4* op = (uint4*)(outb + (size_t)n * HID + o0);
    op[0] = make_uint4(pw[0], pw[1], pw[2], pw[3]);
    op[1] = make_uint4(pw[4], pw[5], pw[6], pw[7]);
}

// ============ sum pool per graph (batch sorted -> run-length accumulate) ======
#define POOL_NODES 128
__global__ void pool_sum(const ushort* __restrict__ h, const int* __restrict__ batch,
                         float* __restrict__ g) {
    __shared__ int sbatch[POOL_NODES];
    int t = threadIdx.x;
    int nbase = blockIdx.x * POOL_NODES;
    for (int i = t; i < POOL_NODES; i += 256) {
        int n = nbase + i;
        sbatch[i] = (n < N_NODES) ? batch[n] : -1;
    }
    __syncthreads();
    int f = t & 31;
    int c0 = (t >> 5) * 16;
    int curb = -1;
    float acc = 0.f;
    for (int j = 0; j < 16; ++j) {
        int li = c0 + j;
        int n = nbase + li;
        if (n >= N_NODES) break;
        int bid = sbatch[li];
        float v = bfu2f((uint)h[(size_t)n * HID + f]);
        if (bid != curb) {
            if (curb >= 0) atomicAdd(&g[curb * HID + f], acc);
            curb = bid;
            acc = 0.f;
        }
        acc += v;
    }
    if (curb >= 0) atomicAdd(&g[curb * HID + f], acc);
}

// ============ head ============
__global__ void head(const float* __restrict__ g, const float* __restrict__ w1,
                     const float* __restrict__ b1, const float* __restrict__ w2,
                     const float* __restrict__ b2, float* __restrict__ out) {
    __shared__ float sW1[HID][HID];
    __shared__ float sW2[HID][2];
    __shared__ float sb1[HID];
    int t = threadIdx.x;  // 512 threads, one graph each
    for (int i = t; i < HID * HID; i += 512) sW1[i / HID][i % HID] = w1[i];
    if (t < HID * 2) sW2[t / 2][t % 2] = w2[t];
    if (t < HID) sb1[t] = b1[t];
    __syncthreads();
    float gi[HID];
#pragma unroll
    for (int k = 0; k < HID; ++k) gi[k] = g[t * HID + k];
    float l0 = b2[0], l1 = b2[1];
#pragma unroll
    for (int o = 0; o < HID; ++o) {
        float a = sb1[o];
#pragma unroll
        for (int k = 0; k < HID; ++k) a += gi[k] * sW1[k][o];
        a = fmaxf(a, 0.f);
        l0 += a * sW2[o][0];
        l1 += a * sW2[o][1];
    }
    float m = fmaxf(l0, l1);
    float lse = m + logf(expf(l0 - m) + expf(l1 - m));
    out[t * 2 + 0] = l0 - lse;
    out[t * 2 + 1] = l1 - lse;
}

extern "C" void kernel_launch(void* const* d_in, const int* in_sizes, int n_in,
                              void* d_out, int out_size, void* d_ws, size_t ws_size,
                              hipStream_t stream) {
    const float* x      = (const float*)d_in[0];
    const float* W_rel1 = (const float*)d_in[1];
    const float* b_rel1 = (const float*)d_in[2];
    const float* W_root1= (const float*)d_in[3];
    const float* W_rel  = (const float*)d_in[4];   // 4 x 32 x 32
    const float* b_rel  = (const float*)d_in[5];   // 4 x 32
    const float* W_root = (const float*)d_in[6];   // 4 x 32 x 32
    const float* lin1_w = (const float*)d_in[7];
    const float* lin1_b = (const float*)d_in[8];
    const float* lin2_w = (const float*)d_in[9];
    const float* lin2_b = (const float*)d_in[10];
    const int*   ei     = (const int*)d_in[11];    // [2, E]: src then dst
    const int*   batch  = (const int*)d_in[12];
    float* out = (float*)d_out;

    const int* src = ei;
    const int* dst = ei + N_EDGES;

    // workspace layout
    int*    cursor = (int*)d_ws;                        // NBUCK (pad to 1024)
    int*    bucket = cursor + 1024;                     // NBUCK * BCAP
    ushort* B0b    = (ushort*)(bucket + NBUCK * BCAP);  // N*32 bf16
    ushort* B1b    = B0b + (size_t)N_NODES * HID;       // N*32 bf16
    float*  g      = (float*)(B1b + (size_t)N_NODES * HID);  // 512*32

    dim3 blk(256);
    dim3 grd_e((N_EDGES + 255) / 256);         // 9766
    dim3 grd_no((N_NODES * HID + 255) / 256);  // 12500
    dim3 grd_cv(NBUCK);                        // 782
    dim3 grd_pl((N_NODES + POOL_NODES - 1) / POOL_NODES);

    // ---- bucket build (replaces histo+scan+fill CSR) ----
    hipMemsetAsync(cursor, 0, 1024 * sizeof(int), stream);
    bucket_fill<<<grd_e, blk, 0, stream>>>(src, dst, cursor, bucket);

    // ---- layer 1: tmp = x@W_rel1 (bf16); h1 = relu(gather(tmp) + b1 + x@W_root1) ----
    gemm14<<<grd_no, blk, 0, stream>>>(x, W_rel1, B0b);
    conv_bucket<false, IN_DIM, false><<<grd_cv, blk, 0, stream>>>(
        bucket, cursor, B0b, (const void*)x, nullptr, b_rel1, W_root1, B1b);

    // ---- layers 2..5: h' = relu(gather(h)@W_rel + b + h@W_root) ----
    ushort* cur = B1b;
    ushort* nxt = B0b;
    for (int i = 0; i < 4; ++i) {
        conv_bucket<true, HID, true><<<grd_cv, blk, 0, stream>>>(
            bucket, cursor, cur, (const void*)cur, W_rel + i * HID * HID,
            b_rel + i * HID, W_root + i * HID * HID, nxt);
        ushort* tswap = cur; cur = nxt; nxt = tswap;
    }
    // final h in `cur`

    // ---- sum pool + head ----
    hipMemsetAsync(g, 0, (size_t)N_GRAPHS * HID * sizeof(float), stream);
    pool_sum<<<grd_pl, blk, 0, stream>>>(cur, batch, g);
    head<<<dim3(1), dim3(512), 0, stream>>>(g, lin1_w, lin1_b, lin2_w, lin2_b, out);
}

// Round 4
// 583.899 us; speedup vs baseline: 5.8338x; 5.8338x over previous
//
#include <hip/hip_runtime.h>
#include <math.h>

#define N_NODES 100000
#define N_EDGES 2500000
#define N_GRAPHS 512
#define IN_DIM 14
#define HID 32
#define CAP 64  // per-node slot capacity; degree ~ Poisson(25), max over 100k ~52-55

typedef unsigned int uint;
typedef unsigned short ushort;

__device__ inline float bflo(uint w) { return __uint_as_float(w << 16); }
__device__ inline float bfhi(uint w) { return __uint_as_float(w & 0xffff0000u); }
__device__ inline ushort f2bf(float f) {
    uint u = __float_as_uint(f);
    return (ushort)((u + 0x7fffu + ((u >> 16) & 1u)) >> 16);  // RNE
}

// ============ one-pass slot fill: 100k counters (25 atomics each — sweet spot) ====
__global__ void fill_slots(const int* __restrict__ src, const int* __restrict__ dst,
                           int* __restrict__ deg, int* __restrict__ slots) {
    int e = blockIdx.x * 256 + threadIdx.x;
    if (e >= N_EDGES) return;
    int d = dst[e];
    int p = atomicAdd(&deg[d], 1);
    if (p < CAP) slots[d * CAP + p] = src[e];
}

// ============ layer-1 pre-GEMM: tmp(bf16) = x @ W_rel1 (14 -> 32) ============
__global__ void gemm14(const float* __restrict__ h, const float* __restrict__ W,
                       ushort* __restrict__ out) {
    __shared__ float sW[IN_DIM][HID];
    int t = threadIdx.x;
    for (int i = t; i < IN_DIM * HID; i += 256) sW[i / HID][i % HID] = W[i];
    __syncthreads();
    int idx = blockIdx.x * 256 + t;  // n*32 + o
    if (idx >= N_NODES * HID) return;
    int n = idx >> 5, o = idx & 31;
    const float* hr = h + (long)n * IN_DIM;
    float acc = 0.f;
#pragma unroll
    for (int k = 0; k < IN_DIM; ++k) acc += hr[k] * sW[k][o];
    out[idx] = f2bf(acc);
}

// ============ fused conv: gather(bf16) + (opt) @Wrel + bias + h@Wroot + relu =====
// 8 lanes per node, each owning 4 of 32 features (uint2 = 8B bf16 per edge).
template <bool MUL_REL, int K, bool ROOT_BF16>
__global__ void conv_fused(const int* __restrict__ deg, const int* __restrict__ slots,
                           const ushort* __restrict__ featb,  // N x 32 bf16 gather table
                           const void* __restrict__ root_in,  // N x K (bf16 or f32)
                           const float* __restrict__ Wrel,    // 32x32 (if MUL_REL)
                           const float* __restrict__ bias,    // 32
                           const float* __restrict__ Wroot,   // K x 32
                           ushort* __restrict__ outb) {       // N x 32 bf16
    __shared__ float sWrel[MUL_REL ? HID * HID : 1];
    __shared__ float sWroot[K * HID];
    __shared__ float sb[HID];
    int t = threadIdx.x;
    if (MUL_REL)
        for (int i = t; i < HID * HID; i += 256) sWrel[i] = Wrel[i];
    for (int i = t; i < K * HID; i += 256) sWroot[i] = Wroot[i];
    if (t < HID) sb[t] = bias[t];
    __syncthreads();

    int n = blockIdx.x * 32 + (t >> 3);  // 3125 blocks * 32 nodes = 100000 exactly
    int q = t & 7;
    int o = q * 4;

    int dn = deg[n]; if (dn > CAP) dn = CAP;
    const int* sl = slots + n * CAP;
    float a0 = 0.f, a1 = 0.f, a2 = 0.f, a3 = 0.f;
    int e = 0;
    for (; e + 2 <= dn; e += 2) {
        int c0 = sl[e], c1 = sl[e + 1];
        uint2 v0 = *(const uint2*)(featb + c0 * HID + o);
        uint2 v1 = *(const uint2*)(featb + c1 * HID + o);
        a0 += bflo(v0.x) + bflo(v1.x);
        a1 += bfhi(v0.x) + bfhi(v1.x);
        a2 += bflo(v0.y) + bflo(v1.y);
        a3 += bfhi(v0.y) + bfhi(v1.y);
    }
    if (e < dn) {
        int c = sl[e];
        uint2 v = *(const uint2*)(featb + c * HID + o);
        a0 += bflo(v.x); a1 += bfhi(v.x); a2 += bflo(v.y); a3 += bfhi(v.y);
    }

    float r0 = sb[o], r1 = sb[o + 1], r2 = sb[o + 2], r3 = sb[o + 3];
    if constexpr (MUL_REL) {
        float a[4] = {a0, a1, a2, a3};
#pragma unroll
        for (int c = 0; c < 8; ++c) {
#pragma unroll
            for (int j = 0; j < 4; ++j) {
                float av = __shfl(a[j], c, 8);
                const float* w = &sWrel[(c * 4 + j) * HID + o];
                r0 += av * w[0]; r1 += av * w[1]; r2 += av * w[2]; r3 += av * w[3];
            }
        }
    } else {
        r0 += a0; r1 += a1; r2 += a2; r3 += a3;
    }

    if constexpr (ROOT_BF16) {
        uint2 h2 = *(const uint2*)((const ushort*)root_in + n * HID + o);
        float hh[4] = {bflo(h2.x), bfhi(h2.x), bflo(h2.y), bfhi(h2.y)};
#pragma unroll
        for (int c = 0; c < 8; ++c) {
#pragma unroll
            for (int j = 0; j < 4; ++j) {
                float hv = __shfl(hh[j], c, 8);
                const float* w = &sWroot[(c * 4 + j) * HID + o];
                r0 += hv * w[0]; r1 += hv * w[1]; r2 += hv * w[2]; r3 += hv * w[3];
            }
        }
    } else {
        const float* hr = (const float*)root_in + (long)n * K;
#pragma unroll
        for (int k = 0; k < K; ++k) {
            float hv = hr[k];
            const float* w = &sWroot[k * HID + o];
            r0 += hv * w[0]; r1 += hv * w[1]; r2 += hv * w[2]; r3 += hv * w[3];
        }
    }

    uint lo = (uint)f2bf(fmaxf(r0, 0.f)) | ((uint)f2bf(fmaxf(r1, 0.f)) << 16);
    uint hi = (uint)f2bf(fmaxf(r2, 0.f)) | ((uint)f2bf(fmaxf(r3, 0.f)) << 16);
    *(uint2*)(outb + n * HID + o) = make_uint2(lo, hi);
}

// ============ sum pool per graph (batch sorted -> run-length accumulate) ======
#define POOL_NODES 128
__global__ void pool_sum(const ushort* __restrict__ h, const int* __restrict__ batch,
                         float* __restrict__ g) {
    __shared__ int sbatch[POOL_NODES];
    int t = threadIdx.x;
    int nbase = blockIdx.x * POOL_NODES;
    for (int i = t; i < POOL_NODES; i += 256) {
        int n = nbase + i;
        sbatch[i] = (n < N_NODES) ? batch[n] : -1;
    }
    __syncthreads();
    int f = t & 31;
    int c0 = (t >> 5) * 16;
    int curb = -1;
    float acc = 0.f;
    for (int j = 0; j < 16; ++j) {
        int li = c0 + j;
        int n = nbase + li;
        if (n >= N_NODES) break;
        int bid = sbatch[li];
        float v = bflo((uint)h[(long)n * HID + f]);
        if (bid != curb) {
            if (curb >= 0) atomicAdd(&g[curb * HID + f], acc);
            curb = bid;
            acc = 0.f;
        }
        acc += v;
    }
    if (curb >= 0) atomicAdd(&g[curb * HID + f], acc);
}

// ============ head: relu(g@W1+b1) @ W2 + b2 -> log_softmax ============
__global__ void head(const float* __restrict__ g, const float* __restrict__ w1,
                     const float* __restrict__ b1, const float* __restrict__ w2,
                     const float* __restrict__ b2, float* __restrict__ out) {
    __shared__ float sW1[HID][HID];
    __shared__ float sW2[HID][2];
    __shared__ float sb1[HID];
    int t = threadIdx.x;  // 512 threads, one graph each
    for (int i = t; i < HID * HID; i += 512) sW1[i / HID][i % HID] = w1[i];
    if (t < HID * 2) sW2[t / 2][t % 2] = w2[t];
    if (t < HID) sb1[t] = b1[t];
    __syncthreads();
    float gi[HID];
#pragma unroll
    for (int k = 0; k < HID; ++k) gi[k] = g[t * HID + k];
    float l0 = b2[0], l1 = b2[1];
#pragma unroll
    for (int o = 0; o < HID; ++o) {
        float a = sb1[o];
#pragma unroll
        for (int k = 0; k < HID; ++k) a += gi[k] * sW1[k][o];
        a = fmaxf(a, 0.f);
        l0 += a * sW2[o][0];
        l1 += a * sW2[o][1];
    }
    float m = fmaxf(l0, l1);
    float lse = m + logf(expf(l0 - m) + expf(l1 - m));
    out[t * 2 + 0] = l0 - lse;
    out[t * 2 + 1] = l1 - lse;
}

extern "C" void kernel_launch(void* const* d_in, const int* in_sizes, int n_in,
                              void* d_out, int out_size, void* d_ws, size_t ws_size,
                              hipStream_t stream) {
    const float* x      = (const float*)d_in[0];
    const float* W_rel1 = (const float*)d_in[1];
    const float* b_rel1 = (const float*)d_in[2];
    const float* W_root1= (const float*)d_in[3];
    const float* W_rel  = (const float*)d_in[4];   // 4 x 32 x 32
    const float* b_rel  = (const float*)d_in[5];   // 4 x 32
    const float* W_root = (const float*)d_in[6];   // 4 x 32 x 32
    const float* lin1_w = (const float*)d_in[7];
    const float* lin1_b = (const float*)d_in[8];
    const float* lin2_w = (const float*)d_in[9];
    const float* lin2_b = (const float*)d_in[10];
    const int*   ei     = (const int*)d_in[11];    // [2, E]: src then dst
    const int*   batch  = (const int*)d_in[12];
    float* out = (float*)d_out;

    const int* src = ei;
    const int* dst = ei + N_EDGES;

    // workspace layout (4B-typed; uint2/uint4 regions are 8/16B aligned by construction)
    int*    deg   = (int*)d_ws;                        // N (pad to N+32)
    int*    slots = deg + N_NODES + 32;                // N * CAP ints (25.6 MB)
    ushort* B0b   = (ushort*)(slots + N_NODES * CAP);  // N*32 bf16
    ushort* B1b   = B0b + (size_t)N_NODES * HID;       // N*32 bf16
    float*  g     = (float*)(B1b + (size_t)N_NODES * HID);  // 512*32 f32

    dim3 blk(256);
    dim3 grd_e((N_EDGES + 255) / 256);         // 9766
    dim3 grd_no((N_NODES * HID + 255) / 256);  // 12500
    dim3 grd_cv(N_NODES / 32);                 // 3125 (exact)
    dim3 grd_pl((N_NODES + POOL_NODES - 1) / POOL_NODES);

    // ---- slot-table build (one pass; no histo/scan) ----
    hipMemsetAsync(deg, 0, N_NODES * sizeof(int), stream);
    fill_slots<<<grd_e, blk, 0, stream>>>(src, dst, deg, slots);

    // ---- layer 1: tmp = x@W_rel1 (bf16); h1 = relu(gather(tmp) + b1 + x@W_root1) ----
    gemm14<<<grd_no, blk, 0, stream>>>(x, W_rel1, B0b);
    conv_fused<false, IN_DIM, false><<<grd_cv, blk, 0, stream>>>(
        deg, slots, B0b, (const void*)x, nullptr, b_rel1, W_root1, B1b);

    // ---- layers 2..5: h' = relu(gather(h)@W_rel + b + h@W_root) ----
    ushort* cur = B1b;
    ushort* nxt = B0b;
    for (int i = 0; i < 4; ++i) {
        conv_fused<true, HID, true><<<grd_cv, blk, 0, stream>>>(
            deg, slots, cur, (const void*)cur, W_rel + i * HID * HID,
            b_rel + i * HID, W_root + i * HID * HID, nxt);
        ushort* tswap = cur; cur = nxt; nxt = tswap;
    }
    // final h in `cur` (B1b)

    // ---- sum pool + head ----
    hipMemsetAsync(g, 0, (size_t)N_GRAPHS * HID * sizeof(float), stream);
    pool_sum<<<grd_pl, blk, 0, stream>>>(cur, batch, g);
    head<<<dim3(1), dim3(512), 0, stream>>>(g, lin1_w, lin1_b, lin2_w, lin2_b, out);
}

// Round 5
// 440.607 us; speedup vs baseline: 7.7311x; 1.3252x over previous
//
#include <hip/hip_runtime.h>
#include <math.h>

#define N_NODES 100000
#define N_EDGES 2500000
#define N_GRAPHS 512
#define IN_DIM 14
#define HID 32
#define CAP 64        // per-node slot capacity; degree ~ Poisson(25), max ~55

// dst-buckets for the two-pass build: bucket = dst >> 7 (128 nodes each)
#define NB 782        // ceil(100000/128)
#define NBP 784       // padded
#define BCAP 4096     // per-bucket capacity (mean 3197, sigma 56 -> +16 sigma)
#define SUBCAP 1024   // per-bank capacity (4 banks; mean ~800, sigma 28 -> +8 sigma)
#define CHUNK 8192    // edges per bin_edges block
#define NBLK ((N_EDGES + CHUNK - 1) / CHUNK)   // 306

typedef unsigned int uint;
typedef unsigned short ushort;

__device__ inline float bflo(uint w) { return __uint_as_float(w << 16); }
__device__ inline float bfhi(uint w) { return __uint_as_float(w & 0xffff0000u); }
__device__ inline ushort f2bf(float f) {
    uint u = __float_as_uint(f);
    return (ushort)((u + 0x7fffu + ((u >> 16) & 1u)) >> 16);  // RNE
}

// ============ pass 1: coarse-bin edges by dst bucket (dense run writes) =======
__global__ void bin_edges(const int* __restrict__ src, const int* __restrict__ dst,
                          int* __restrict__ gcur, int* __restrict__ binned) {
    __shared__ int scnt[NBP];
    __shared__ int sbase[NBP];
    __shared__ int soff[NBP];
    int t = threadIdx.x;
    for (int i = t; i < NBP; i += 256) { scnt[i] = 0; soff[i] = 0; }
    __syncthreads();
    int base = blockIdx.x * CHUNK;
    int bank = blockIdx.x & 3;
    // phase i: count per bucket
    for (int j = 0; j < CHUNK; j += 256) {
        int e = base + j + t;
        if (e < N_EDGES) atomicAdd(&scnt[dst[e] >> 7], 1);
    }
    __syncthreads();
    // phase ii: one global reservation per (bucket, block)
    for (int b = t; b < NBP; b += 256) {
        int c = scnt[b];
        sbase[b] = (c > 0) ? atomicAdd(&gcur[b * 4 + bank], c) : 0;
    }
    __syncthreads();
    // phase iii: re-read edges (L2-hot), write packed runs
    for (int j = 0; j < CHUNK; j += 256) {
        int e = base + j + t;
        if (e < N_EDGES) {
            int d = dst[e];
            int b = d >> 7;
            int pos = sbase[b] + atomicAdd(&soff[b], 1);
            if (pos < SUBCAP)
                binned[b * BCAP + bank * SUBCAP + pos] = (src[e] << 7) | (d & 127);
        }
    }
}

// ============ pass 2: assemble 128x64 slot tile in LDS, stream out ============
__global__ void build_slots(const int* __restrict__ gcur, const int* __restrict__ binned,
                            int* __restrict__ deg, int* __restrict__ slots) {
    __shared__ int stile[128 * CAP];  // 32 KB (garbage beyond deg never read)
    __shared__ int sdeg[128];
    int t = threadIdx.x;
    if (t < 128) sdeg[t] = 0;
    __syncthreads();
    int b = blockIdx.x;
#pragma unroll
    for (int k = 0; k < 4; ++k) {
        int cnt = gcur[b * 4 + k]; if (cnt > SUBCAP) cnt = SUBCAP;
        const int* seg = binned + b * BCAP + k * SUBCAP;
        for (int i = t; i < cnt; i += 256) {
            int w = seg[i];
            int ld = w & 127, sn = w >> 7;
            int p = atomicAdd(&sdeg[ld], 1);
            if (p < CAP) stile[ld * CAP + p] = sn;
        }
    }
    __syncthreads();
    int nbase = b * 128;
    int rows = N_NODES - nbase; if (rows > 128) rows = 128;
    int total4 = rows * CAP / 4;  // int4 count
    int4* dstp = (int4*)(slots + (size_t)nbase * CAP);
    const int4* srcp = (const int4*)stile;
    for (int i = t; i < total4; i += 256) dstp[i] = srcp[i];
    if (t < rows) {
        int dv = sdeg[t]; if (dv > CAP) dv = CAP;
        deg[nbase + t] = dv;
    }
}

// ============ layer-1 pre-GEMM: tmp(bf16) = x @ W_rel1 (14 -> 32) ============
__global__ void gemm14(const float* __restrict__ h, const float* __restrict__ W,
                       ushort* __restrict__ out) {
    __shared__ float sW[IN_DIM][HID];
    int t = threadIdx.x;
    for (int i = t; i < IN_DIM * HID; i += 256) sW[i / HID][i % HID] = W[i];
    __syncthreads();
    int idx = blockIdx.x * 256 + t;  // n*32 + o
    if (idx >= N_NODES * HID) return;
    int n = idx >> 5, o = idx & 31;
    const float* hr = h + (long)n * IN_DIM;
    float acc = 0.f;
#pragma unroll
    for (int k = 0; k < IN_DIM; ++k) acc += hr[k] * sW[k][o];
    out[idx] = f2bf(acc);
}

// ============ fused conv: gather(bf16) + (opt) @Wrel + bias + h@Wroot + relu =====
// 8 lanes per node, each owning 4 of 32 features (uint2 = 8B bf16 per edge).
template <bool MUL_REL, int K, bool ROOT_BF16>
__global__ void conv_fused(const int* __restrict__ deg, const int* __restrict__ slots,
                           const ushort* __restrict__ featb,  // N x 32 bf16 gather table
                           const void* __restrict__ root_in,  // N x K (bf16 or f32)
                           const float* __restrict__ Wrel,    // 32x32 (if MUL_REL)
                           const float* __restrict__ bias,    // 32
                           const float* __restrict__ Wroot,   // K x 32
                           ushort* __restrict__ outb) {       // N x 32 bf16
    __shared__ float sWrel[MUL_REL ? HID * HID : 1];
    __shared__ float sWroot[K * HID];
    __shared__ float sb[HID];
    int t = threadIdx.x;
    if (MUL_REL)
        for (int i = t; i < HID * HID; i += 256) sWrel[i] = Wrel[i];
    for (int i = t; i < K * HID; i += 256) sWroot[i] = Wroot[i];
    if (t < HID) sb[t] = bias[t];
    __syncthreads();

    int n = blockIdx.x * 32 + (t >> 3);  // 3125 blocks * 32 nodes = 100000 exactly
    int q = t & 7;
    int o = q * 4;

    int dn = deg[n]; if (dn > CAP) dn = CAP;
    const int* sl = slots + n * CAP;
    float a0 = 0.f, a1 = 0.f, a2 = 0.f, a3 = 0.f;
    int e = 0;
    for (; e + 2 <= dn; e += 2) {
        int c0 = sl[e], c1 = sl[e + 1];
        uint2 v0 = *(const uint2*)(featb + c0 * HID + o);
        uint2 v1 = *(const uint2*)(featb + c1 * HID + o);
        a0 += bflo(v0.x) + bflo(v1.x);
        a1 += bfhi(v0.x) + bfhi(v1.x);
        a2 += bflo(v0.y) + bflo(v1.y);
        a3 += bfhi(v0.y) + bfhi(v1.y);
    }
    if (e < dn) {
        int c = sl[e];
        uint2 v = *(const uint2*)(featb + c * HID + o);
        a0 += bflo(v.x); a1 += bfhi(v.x); a2 += bflo(v.y); a3 += bfhi(v.y);
    }

    float r0 = sb[o], r1 = sb[o + 1], r2 = sb[o + 2], r3 = sb[o + 3];
    if constexpr (MUL_REL) {
        float a[4] = {a0, a1, a2, a3};
#pragma unroll
        for (int c = 0; c < 8; ++c) {
#pragma unroll
            for (int j = 0; j < 4; ++j) {
                float av = __shfl(a[j], c, 8);
                const float* w = &sWrel[(c * 4 + j) * HID + o];
                r0 += av * w[0]; r1 += av * w[1]; r2 += av * w[2]; r3 += av * w[3];
            }
        }
    } else {
        r0 += a0; r1 += a1; r2 += a2; r3 += a3;
    }

    if constexpr (ROOT_BF16) {
        uint2 h2 = *(const uint2*)((const ushort*)root_in + n * HID + o);
        float hh[4] = {bflo(h2.x), bfhi(h2.x), bflo(h2.y), bfhi(h2.y)};
#pragma unroll
        for (int c = 0; c < 8; ++c) {
#pragma unroll
            for (int j = 0; j < 4; ++j) {
                float hv = __shfl(hh[j], c, 8);
                const float* w = &sWroot[(c * 4 + j) * HID + o];
                r0 += hv * w[0]; r1 += hv * w[1]; r2 += hv * w[2]; r3 += hv * w[3];
            }
        }
    } else {
        const float* hr = (const float*)root_in + (long)n * K;
#pragma unroll
        for (int k = 0; k < K; ++k) {
            float hv = hr[k];
            const float* w = &sWroot[k * HID + o];
            r0 += hv * w[0]; r1 += hv * w[1]; r2 += hv * w[2]; r3 += hv * w[3];
        }
    }

    uint lo = (uint)f2bf(fmaxf(r0, 0.f)) | ((uint)f2bf(fmaxf(r1, 0.f)) << 16);
    uint hi = (uint)f2bf(fmaxf(r2, 0.f)) | ((uint)f2bf(fmaxf(r3, 0.f)) << 16);
    *(uint2*)(outb + n * HID + o) = make_uint2(lo, hi);
}

// ============ sum pool per graph (batch sorted -> run-length accumulate) ======
#define POOL_NODES 128
__global__ void pool_sum(const ushort* __restrict__ h, const int* __restrict__ batch,
                         float* __restrict__ g) {
    __shared__ int sbatch[POOL_NODES];
    int t = threadIdx.x;
    int nbase = blockIdx.x * POOL_NODES;
    for (int i = t; i < POOL_NODES; i += 256) {
        int n = nbase + i;
        sbatch[i] = (n < N_NODES) ? batch[n] : -1;
    }
    __syncthreads();
    int f = t & 31;
    int c0 = (t >> 5) * 16;
    int curb = -1;
    float acc = 0.f;
    for (int j = 0; j < 16; ++j) {
        int li = c0 + j;
        int n = nbase + li;
        if (n >= N_NODES) break;
        int bid = sbatch[li];
        float v = bflo((uint)h[(long)n * HID + f]);
        if (bid != curb) {
            if (curb >= 0) atomicAdd(&g[curb * HID + f], acc);
            curb = bid;
            acc = 0.f;
        }
        acc += v;
    }
    if (curb >= 0) atomicAdd(&g[curb * HID + f], acc);
}

// ============ head: relu(g@W1+b1) @ W2 + b2 -> log_softmax ============
__global__ void head(const float* __restrict__ g, const float* __restrict__ w1,
                     const float* __restrict__ b1, const float* __restrict__ w2,
                     const float* __restrict__ b2, float* __restrict__ out) {
    __shared__ float sW1[HID][HID];
    __shared__ float sW2[HID][2];
    __shared__ float sb1[HID];
    int t = threadIdx.x;  // 512 threads, one graph each
    for (int i = t; i < HID * HID; i += 512) sW1[i / HID][i % HID] = w1[i];
    if (t < HID * 2) sW2[t / 2][t % 2] = w2[t];
    if (t < HID) sb1[t] = b1[t];
    __syncthreads();
    float gi[HID];
#pragma unroll
    for (int k = 0; k < HID; ++k) gi[k] = g[t * HID + k];
    float l0 = b2[0], l1 = b2[1];
#pragma unroll
    for (int o = 0; o < HID; ++o) {
        float a = sb1[o];
#pragma unroll
        for (int k = 0; k < HID; ++k) a += gi[k] * sW1[k][o];
        a = fmaxf(a, 0.f);
        l0 += a * sW2[o][0];
        l1 += a * sW2[o][1];
    }
    float m = fmaxf(l0, l1);
    float lse = m + logf(expf(l0 - m) + expf(l1 - m));
    out[t * 2 + 0] = l0 - lse;
    out[t * 2 + 1] = l1 - lse;
}

extern "C" void kernel_launch(void* const* d_in, const int* in_sizes, int n_in,
                              void* d_out, int out_size, void* d_ws, size_t ws_size,
                              hipStream_t stream) {
    const float* x      = (const float*)d_in[0];
    const float* W_rel1 = (const float*)d_in[1];
    const float* b_rel1 = (const float*)d_in[2];
    const float* W_root1= (const float*)d_in[3];
    const float* W_rel  = (const float*)d_in[4];   // 4 x 32 x 32
    const float* b_rel  = (const float*)d_in[5];   // 4 x 32
    const float* W_root = (const float*)d_in[6];   // 4 x 32 x 32
    const float* lin1_w = (const float*)d_in[7];
    const float* lin1_b = (const float*)d_in[8];
    const float* lin2_w = (const float*)d_in[9];
    const float* lin2_b = (const float*)d_in[10];
    const int*   ei     = (const int*)d_in[11];    // [2, E]: src then dst
    const int*   batch  = (const int*)d_in[12];
    float* out = (float*)d_out;

    const int* src = ei;
    const int* dst = ei + N_EDGES;

    // workspace layout (all offsets 16B-aligned by construction)
    int*    gcur   = (int*)d_ws;                        // NBP*4 = 3136, pad to 3200
    int*    binned = gcur + 3200;                       // NB * BCAP (12.8 MB)
    int*    deg    = binned + NB * BCAP;                // N (pad to N+32)
    int*    slots  = deg + N_NODES + 32;                // N * CAP (25.6 MB)
    ushort* B0b    = (ushort*)(slots + (size_t)N_NODES * CAP);  // N*32 bf16
    ushort* B1b    = B0b + (size_t)N_NODES * HID;               // N*32 bf16
    float*  g      = (float*)(B1b + (size_t)N_NODES * HID);     // 512*32 f32

    dim3 blk(256);
    dim3 grd_no((N_NODES * HID + 255) / 256);  // 12500
    dim3 grd_cv(N_NODES / 32);                 // 3125 (exact)
    dim3 grd_pl((N_NODES + POOL_NODES - 1) / POOL_NODES);

    // ---- two-pass slot-table build ----
    hipMemsetAsync(gcur, 0, 3200 * sizeof(int), stream);
    bin_edges<<<dim3(NBLK), blk, 0, stream>>>(src, dst, gcur, binned);
    build_slots<<<dim3(NB), blk, 0, stream>>>(gcur, binned, deg, slots);

    // ---- layer 1: tmp = x@W_rel1 (bf16); h1 = relu(gather(tmp) + b1 + x@W_root1) ----
    gemm14<<<grd_no, blk, 0, stream>>>(x, W_rel1, B0b);
    conv_fused<false, IN_DIM, false><<<grd_cv, blk, 0, stream>>>(
        deg, slots, B0b, (const void*)x, nullptr, b_rel1, W_root1, B1b);

    // ---- layers 2..5: h' = relu(gather(h)@W_rel + b + h@W_root) ----
    ushort* cur = B1b;
    ushort* nxt = B0b;
    for (int i = 0; i < 4; ++i) {
        conv_fused<true, HID, true><<<grd_cv, blk, 0, stream>>>(
            deg, slots, cur, (const void*)cur, W_rel + i * HID * HID,
            b_rel + i * HID, W_root + i * HID * HID, nxt);
        ushort* tswap = cur; cur = nxt; nxt = tswap;
    }
    // final h in `cur`

    // ---- sum pool + head ----
    hipMemsetAsync(g, 0, (size_t)N_GRAPHS * HID * sizeof(float), stream);
    pool_sum<<<grd_pl, blk, 0, stream>>>(cur, batch, g);
    head<<<dim3(1), dim3(512), 0, stream>>>(g, lin1_w, lin1_b, lin2_w, lin2_b, out);
}